// Round 15
// baseline (118.248 us; speedup 1.0000x reference)
//
#include <hip/hip_runtime.h>

#define B_N 256
#define IC_N 1152
#define J_N 10
#define D_N 16

typedef __attribute__((ext_vector_type(8))) short short8;
typedef __attribute__((ext_vector_type(4))) float floatx4;

union u4s8 { uint4 u; short8 s; };

__device__ __forceinline__ float bf_lo(unsigned int u){
  union { unsigned int i; float f; } c; c.i = u << 16; return c.f;
}
__device__ __forceinline__ float bf_hi(unsigned int u){
  union { unsigned int i; float f; } c; c.i = u & 0xffff0000u; return c.f;
}
__device__ __forceinline__ unsigned int rne16(float f){
  union { float ff; unsigned int i; } c; c.ff = f;
  return (c.i + 0x7FFFu + ((c.i >> 16) & 1u)) >> 16;
}
__device__ __forceinline__ unsigned int pack_rne(float lo, float hi){
  return rne16(lo) | (rne16(hi) << 16);
}
__device__ __forceinline__ unsigned int pack_trunc(float lo, float hi){
  union { float f; unsigned int u; } a, b; a.f = lo; b.f = hi;
  return __builtin_amdgcn_perm(b.u, a.u, 0x07060302u);
}

// prep (R14-proven, unchanged): W once -> wsf + wcc2 frags; zero vsum.
__global__ __launch_bounds__(256) void caps_prep(
    const float* __restrict__ W, uint4* __restrict__ wsf,
    uint4* __restrict__ wcc2, float* __restrict__ vsum)
{
  const int tid = threadIdx.x;
  const int t0 = blockIdx.x * 256 + tid;
  if (t0 < B_N * J_N * D_N) vsum[t0] = 0.f;
  __shared__ unsigned int lw[1024];
  const int j = blockIdx.x / 72, itile = blockIdx.x % 72;
  const float4* Wt = (const float4*)(W + ((size_t)(j * IC_N + itile * 16) << 7));
  #pragma unroll
  for (int h = 0; h < 2; ++h) {
    const float4 f = Wt[h * 256 + tid];
    lw[(h * 256 + tid) * 2]     = pack_rne(f.x, f.y);
    lw[(h * 256 + tid) * 2 + 1] = pack_rne(f.z, f.w);
  }
  __syncthreads();
  {  // wsf emit (layout verified R5..R14)
    const int ktl = tid >> 6, ln = tid & 63;
    const int base = (ktl * 4 + (ln >> 4)) * 64 + (ln & 15) * 4;
    uint4 q;
    q.x = lw[base]; q.y = lw[base + 1]; q.z = lw[base + 2]; q.w = lw[base + 3];
    wsf[((size_t)j * 288 + itile * 4 + ktl) * 64 + ln] = q;
  }
  {  // wcc2 emit (layout verified R6..R14)
    const int e = tid >> 5, lane2 = tid & 31;
    const int il = lane2 & 15, dbase = (lane2 >> 4) * 8;
    unsigned short h[8];
    #pragma unroll
    for (int k = 0; k < 8; ++k) {
      const unsigned int u = lw[il * 64 + (dbase + k) * 4 + (e >> 1)];
      h[k] = (e & 1) ? (unsigned short)(u >> 16) : (unsigned short)(u & 0xffffu);
    }
    uint4 q;
    q.x = h[0] | ((unsigned int)h[1] << 16);
    q.y = h[2] | ((unsigned int)h[3] << 16);
    q.z = h[4] | ((unsigned int)h[5] << 16);
    q.w = h[6] | ((unsigned int)h[7] << 16);
    wcc2[(((size_t)j * 8 + e) * 72 + itile) * 32 + lane2] = q;
  }
}

// Pass: 32 b per block (two M=16 halves SHARING all W fragments -> W traffic
// halves vs R14). grid (8 btiles32, 72 chunks16), 640 thr = 10 waves (= j).
// Sequential h-loop keeps registers low (no cross-barrier hoists — R13 lesson).
__global__ __launch_bounds__(640, 5) void caps_pass(
    const float* __restrict__ x,
    const uint4* __restrict__ wsf, const uint4* __restrict__ wcc2,
    const uint4* __restrict__ vsbf, float* __restrict__ s_part, const int round)
{
  __shared__ float ccl[10 * 16 * 33];      // [j][i16][b pad33], 21.1 KB
  __shared__ unsigned int xt[16 * 33 * 4]; // [i][b pad33] uint4, 8.4 KB

  const int tid  = threadIdx.x;
  const int wave = tid >> 6;               // = j
  const int lane = tid & 63;
  const int quad = lane >> 4;
  const int col  = lane & 15;
  const int b0   = blockIdx.x << 5;        // 32 b per block
  const int i0   = blockIdx.y << 4;        // 16 i per chunk

  // ---- stage x tile (32 b x 16 i), coalesced 512-B runs per b ----
  for (int p = tid; p < 1024; p += 640) {
    const int b = p >> 5, u = p & 31, i = u >> 1, half = u & 1;
    const float4 v = ((const float4*)(x + ((size_t)((b0 + b) * IC_N + i0 + i) << 3)))[half];
    const int idx = ((i * 33 + b) << 2) + (half << 1);
    xt[idx]     = pack_rne(v.x, v.y);
    xt[idx + 1] = pack_rne(v.z, v.w);
  }
  __syncthreads();
  const uint4* xtq = (const uint4*)xt;

  if (round > 0) {
    uint4 bvq[8];                          // W cc-frags: loaded ONCE, both halves
    #pragma unroll
    for (int e = 0; e < 8; ++e) {
      uint4 q = {0u, 0u, 0u, 0u};
      if (lane < 32)
        q = wcc2[(((size_t)wave * 8 + e) * 72 + blockIdx.y) * 32 + lane];
      bvq[e] = q;
    }
    #pragma unroll
    for (int h = 0; h < 2; ++h) {
      short8 av = {0,0,0,0,0,0,0,0};       // vsum[b=h*16+col][d]; q2,3 K-pad
      if (quad < 2)
        av = *(const short8*)&vsbf[((size_t)(b0 + h * 16 + col) * J_N + wave) * 2 + quad];
      uint4 xr[4];                         // x[b=h*16+quad*4+r][i=col] from LDS
      #pragma unroll
      for (int r = 0; r < 4; ++r)
        xr[r] = xtq[col * 33 + h * 16 + quad * 4 + r];
      floatx4 cc4 = {0.f, 0.f, 0.f, 0.f};
      #pragma unroll
      for (int e = 0; e < 8; ++e) {
        u4s8 bv; bv.u = bvq[e];
        floatx4 tf = {0.f, 0.f, 0.f, 0.f};
        tf = __builtin_amdgcn_mfma_f32_16x16x32_bf16(av, bv.s, tf, 0, 0, 0);
        #pragma unroll
        for (int r = 0; r < 4; ++r) {
          const unsigned int u = ((const unsigned int*)&xr[r])[e >> 1];
          const float xe = (e & 1) ? bf_hi(u) : bf_lo(u);
          cc4[r] += tf[r] * xe;
        }
      }
      #pragma unroll
      for (int r = 0; r < 4; ++r)
        ccl[(wave * 16 + col) * 33 + h * 16 + quad * 4 + r] = cc4[r];
    }
    __syncthreads();
    if (tid < 512) {                       // softmax over j per (i, b32)
      const int i = tid >> 5, b = tid & 31;
      float cc[10];
      #pragma unroll
      for (int j = 0; j < 10; ++j) cc[j] = ccl[(j * 16 + i) * 33 + b];
      float m = cc[0];
      #pragma unroll
      for (int j = 1; j < 10; ++j) m = fmaxf(m, cc[j]);
      float den = 0.f;
      #pragma unroll
      for (int j = 0; j < 10; ++j) { cc[j] = __expf(cc[j] - m); den += cc[j]; }
      const float rd = __builtin_amdgcn_rcpf(den);
      #pragma unroll
      for (int j = 0; j < 10; ++j) ccl[(j * 16 + i) * 33 + b] = cc[j] * rd;
    }
    __syncthreads();
  }

  // ---- phase B: s[b,d] += (c*x) @ Ws; wf loaded ONCE, both halves ----
  uint4 wf[4];
  #pragma unroll
  for (int kt = 0; kt < 4; ++kt)
    wf[kt] = wsf[((size_t)wave * 288 + (blockIdx.y << 2) + kt) * 64 + lane];
  #pragma unroll
  for (int h = 0; h < 2; ++h) {
    floatx4 acc = {0.f, 0.f, 0.f, 0.f};
    #pragma unroll
    for (int kt = 0; kt < 4; ++kt) {
      const int il = kt * 4 + quad;
      const uint4 xq = xtq[il * 33 + h * 16 + col];
      const float c = (round > 0) ? ccl[(wave * 16 + il) * 33 + h * 16 + col] : 0.1f;
      short8 af;
      unsigned int* aq = (unsigned int*)&af;
      aq[0] = pack_trunc(bf_lo(xq.x) * c, bf_hi(xq.x) * c);
      aq[1] = pack_trunc(bf_lo(xq.y) * c, bf_hi(xq.y) * c);
      aq[2] = pack_trunc(bf_lo(xq.z) * c, bf_hi(xq.z) * c);
      aq[3] = pack_trunc(bf_lo(xq.w) * c, bf_hi(xq.w) * c);
      u4s8 bw; bw.u = wf[kt];
      acc = __builtin_amdgcn_mfma_f32_16x16x32_bf16(af, bw.s, acc, 0, 0, 0);
    }
    // s_part[btile16 = 2*bid.x+h][j][b16=quad*4+r][ch72][d=col] (squash-compat)
    float* sp = s_part + ((((size_t)(blockIdx.x * 2 + h) * 10 + wave) * 16
                           + quad * 4) * 72 + blockIdx.y) * 16 + col;
    #pragma unroll
    for (int r = 0; r < 4; ++r) sp[(size_t)r * 72 * 16] = acc[r];
  }
}

// squash (R9/R14-proven, unchanged): one wave per (b,j); 18 coalesced loads;
// vsbf holds ACCUMULATED v-sum (R7 lesson).
__global__ __launch_bounds__(256) void caps_squash(
    const float* __restrict__ s_part, float* __restrict__ vsum,
    unsigned int* __restrict__ vsbf_u, float* __restrict__ out, const int round)
{
  const int tid  = threadIdx.x;
  const int w    = tid >> 6;
  const int lane = tid & 63;
  const int bj   = blockIdx.x * 4 + w;
  const int b    = bj / 10, j = bj - b * 10;
  const int btile = b >> 4, brem = b & 15;
  const float* base = s_part + (((size_t)btile * 10 + j) * 16 + brem) * 1152;
  float acc = 0.f;
  #pragma unroll
  for (int q = 0; q < 18; ++q) acc += base[q * 64 + lane];
  acc += __shfl_xor(acc, 16, 64);
  acc += __shfl_xor(acc, 32, 64);
  const float s = acc;
  float sq = s * s;
  sq += __shfl_xor(sq, 1, 16);
  sq += __shfl_xor(sq, 2, 16);
  sq += __shfl_xor(sq, 4, 16);
  sq += __shfl_xor(sq, 8, 16);
  const float coef = (sq / (1.f + sq)) * rsqrtf(sq + 1e-7f);
  const float v = coef * s;
  if (round < 2) {
    const float vprev = (lane < 16) ? vsum[bj * 16 + lane] : 0.f;
    const float vt = vprev + v;
    const float vtn = __shfl_down(vt, 1, 64);
    if (lane < 16) {
      vsum[bj * 16 + lane] = vt;
      if (!(lane & 1))
        vsbf_u[bj * 8 + (lane >> 1)] = pack_rne(vt, vtn);
    }
  } else if (lane < 16) {
    out[bj * 16 + lane] = v;
  }
}

extern "C" void kernel_launch(void* const* d_in, const int* in_sizes, int n_in,
                              void* d_out, int out_size, void* d_ws, size_t ws_size,
                              hipStream_t stream)
{
  const float* x_p = (const float*)d_in[0];   // [256][1152][8] fp32
  const float* W_p = (const float*)d_in[1];   // [10][1152][16][8] fp32

  // ws: wsf 2.95M | wcc2 2.95M | s_part 11.8M | vsum 164K | vsbf 82K (~18 MB)
  uint4* wsf   = (uint4*)d_ws;
  uint4* wcc2  = wsf + 184320;
  float* s_prt = (float*)(wcc2 + 184320);             // 2949120 f
  float* vsum  = s_prt + 2949120;                     // 40960 f
  unsigned int* vsbf_u = (unsigned int*)(vsum + 40960);
  float* out_p = (float*)d_out;

  caps_prep<<<dim3(720), dim3(256), 0, stream>>>(W_p, wsf, wcc2, vsum);
  for (int r = 0; r < 3; ++r) {
    caps_pass<<<dim3(8, 72), dim3(640), 0, stream>>>(
        x_p, wsf, wcc2, (const uint4*)vsbf_u, s_prt, r);
    caps_squash<<<dim3(640), dim3(256), 0, stream>>>(
        s_prt, vsum, vsbf_u, out_p, r);
  }
}

// Round 16
// 116.907 us; speedup vs baseline: 1.0115x; 1.0115x over previous
//
#include <hip/hip_runtime.h>

#define B_N 256
#define IC_N 1152
#define J_N 10
#define D_N 16

typedef __attribute__((ext_vector_type(8))) short short8;
typedef __attribute__((ext_vector_type(4))) float floatx4;

union u4s8 { uint4 u; short8 s; };

__device__ __forceinline__ float bf_lo(unsigned int u){
  union { unsigned int i; float f; } c; c.i = u << 16; return c.f;
}
__device__ __forceinline__ float bf_hi(unsigned int u){
  union { unsigned int i; float f; } c; c.i = u & 0xffff0000u; return c.f;
}
__device__ __forceinline__ unsigned int rne16(float f){
  union { float ff; unsigned int i; } c; c.ff = f;
  return (c.i + 0x7FFFu + ((c.i >> 16) & 1u)) >> 16;
}
__device__ __forceinline__ unsigned int pack_rne(float lo, float hi){
  return rne16(lo) | (rne16(hi) << 16);
}
__device__ __forceinline__ unsigned int pack_trunc(float lo, float hi){
  union { float f; unsigned int u; } a, b; a.f = lo; b.f = hi;
  return __builtin_amdgcn_perm(b.u, a.u, 0x07060302u);
}

// prep (R14-proven, unchanged): W once -> wsf + wcc2 frags; zero vsum.
__global__ __launch_bounds__(256) void caps_prep(
    const float* __restrict__ W, uint4* __restrict__ wsf,
    uint4* __restrict__ wcc2, float* __restrict__ vsum)
{
  const int tid = threadIdx.x;
  const int t0 = blockIdx.x * 256 + tid;
  if (t0 < B_N * J_N * D_N) vsum[t0] = 0.f;
  __shared__ unsigned int lw[1024];
  const int j = blockIdx.x / 72, itile = blockIdx.x % 72;
  const float4* Wt = (const float4*)(W + ((size_t)(j * IC_N + itile * 16) << 7));
  #pragma unroll
  for (int h = 0; h < 2; ++h) {
    const float4 f = Wt[h * 256 + tid];
    lw[(h * 256 + tid) * 2]     = pack_rne(f.x, f.y);
    lw[(h * 256 + tid) * 2 + 1] = pack_rne(f.z, f.w);
  }
  __syncthreads();
  {  // wsf emit (layout verified R5..R15)
    const int ktl = tid >> 6, ln = tid & 63;
    const int base = (ktl * 4 + (ln >> 4)) * 64 + (ln & 15) * 4;
    uint4 q;
    q.x = lw[base]; q.y = lw[base + 1]; q.z = lw[base + 2]; q.w = lw[base + 3];
    wsf[((size_t)j * 288 + itile * 4 + ktl) * 64 + ln] = q;
  }
  {  // wcc2 emit (layout verified R6..R15)
    const int e = tid >> 5, lane2 = tid & 31;
    const int il = lane2 & 15, dbase = (lane2 >> 4) * 8;
    unsigned short h[8];
    #pragma unroll
    for (int k = 0; k < 8; ++k) {
      const unsigned int u = lw[il * 64 + (dbase + k) * 4 + (e >> 1)];
      h[k] = (e & 1) ? (unsigned short)(u >> 16) : (unsigned short)(u & 0xffffu);
    }
    uint4 q;
    q.x = h[0] | ((unsigned int)h[1] << 16);
    q.y = h[2] | ((unsigned int)h[3] << 16);
    q.z = h[4] | ((unsigned int)h[5] << 16);
    q.w = h[6] | ((unsigned int)h[7] << 16);
    wcc2[(((size_t)j * 8 + e) * 72 + itile) * 32 + lane2] = q;
  }
}

// Pass: HALF-SIZE blocks — 320 thr = 5 waves, each wave does j = 2w, 2w+1
// sequentially. Same 16b x 16i tile, same math, same s_part layout as R14.
// Rationale: 640-thr blocks gave only 2 resident blocks/CU and 10-wave
// barrier convoys (R5..R15 plateau, all counters <15%); 320-thr doubles
// residency to 4 blocks/CU and halves convoy width.
__global__ __launch_bounds__(320, 5) void caps_pass(
    const float* __restrict__ x,
    const uint4* __restrict__ wsf, const uint4* __restrict__ wcc2,
    const uint4* __restrict__ vsbf, float* __restrict__ s_part, const int round)
{
  __shared__ float ccl[10 * 16 * 17];      // [j][i16][b pad17], 10.6 KB
  __shared__ unsigned int xt[16 * 17 * 4]; // [i][b pad17] uint4,  4.3 KB

  const int tid  = threadIdx.x;
  const int wave = tid >> 6;               // 0..4
  const int lane = tid & 63;
  const int quad = lane >> 4;
  const int col  = lane & 15;
  const int b0   = blockIdx.x << 4;        // 16 b
  const int i0   = blockIdx.y << 4;        // 16 i

  // ---- stage x tile (16 b x 16 i): 512 float4 tasks over 320 threads ----
  for (int p = tid; p < 512; p += 320) {
    const int b = p >> 5, u = p & 31, i = u >> 1, half = u & 1;
    const float4 v = ((const float4*)(x + ((size_t)((b0 + b) * IC_N + i0 + i) << 3)))[half];
    const int idx = ((i * 17 + b) << 2) + (half << 1);
    xt[idx]     = pack_rne(v.x, v.y);
    xt[idx + 1] = pack_rne(v.z, v.w);
  }
  __syncthreads();
  const uint4* xtq = (const uint4*)xt;

  if (round > 0) {
    uint4 xr[4];                           // x[b=quad*4+r][i=col] (both j's)
    #pragma unroll
    for (int r = 0; r < 4; ++r)
      xr[r] = xtq[col * 17 + quad * 4 + r];
    #pragma unroll
    for (int jj = 0; jj < 2; ++jj) {
      const int j = wave * 2 + jj;
      short8 av = {0,0,0,0,0,0,0,0};       // vsum[b=col][d]; quads 2,3 K-pad
      if (quad < 2)
        av = *(const short8*)&vsbf[((size_t)(b0 + col) * J_N + j) * 2 + quad];
      uint4 bvq[8];
      #pragma unroll
      for (int e = 0; e < 8; ++e) {
        uint4 q = {0u, 0u, 0u, 0u};
        if (lane < 32)
          q = wcc2[(((size_t)j * 8 + e) * 72 + blockIdx.y) * 32 + lane];
        bvq[e] = q;
      }
      floatx4 cc4 = {0.f, 0.f, 0.f, 0.f};
      #pragma unroll
      for (int e = 0; e < 8; ++e) {
        u4s8 bv; bv.u = bvq[e];
        floatx4 tf = {0.f, 0.f, 0.f, 0.f};
        tf = __builtin_amdgcn_mfma_f32_16x16x32_bf16(av, bv.s, tf, 0, 0, 0);
        #pragma unroll
        for (int r = 0; r < 4; ++r) {
          const unsigned int u = ((const unsigned int*)&xr[r])[e >> 1];
          const float xe = (e & 1) ? bf_hi(u) : bf_lo(u);
          cc4[r] += tf[r] * xe;
        }
      }
      #pragma unroll
      for (int r = 0; r < 4; ++r)
        ccl[(j * 16 + col) * 17 + quad * 4 + r] = cc4[r];
    }
    __syncthreads();
    if (tid < 256) {                       // softmax over j per (i,b), in place
      const int i = tid >> 4, b = tid & 15;
      float cc[10];
      #pragma unroll
      for (int j = 0; j < 10; ++j) cc[j] = ccl[(j * 16 + i) * 17 + b];
      float m = cc[0];
      #pragma unroll
      for (int j = 1; j < 10; ++j) m = fmaxf(m, cc[j]);
      float den = 0.f;
      #pragma unroll
      for (int j = 0; j < 10; ++j) { cc[j] = __expf(cc[j] - m); den += cc[j]; }
      const float rd = __builtin_amdgcn_rcpf(den);
      #pragma unroll
      for (int j = 0; j < 10; ++j) ccl[(j * 16 + i) * 17 + b] = cc[j] * rd;
    }
    __syncthreads();
  }

  // ---- phase B: s[b,d] += (c*x) @ Ws, K=128, per wave's two j ----
  #pragma unroll
  for (int jj = 0; jj < 2; ++jj) {
    const int j = wave * 2 + jj;
    floatx4 acc = {0.f, 0.f, 0.f, 0.f};
    #pragma unroll
    for (int kt = 0; kt < 4; ++kt) {
      const int il = kt * 4 + quad;
      const uint4 xq = xtq[il * 17 + col];
      const uint4 wf = wsf[((size_t)j * 288 + (blockIdx.y << 2) + kt) * 64 + lane];
      const float c = (round > 0) ? ccl[(j * 16 + il) * 17 + col] : 0.1f;
      short8 af;
      unsigned int* aq = (unsigned int*)&af;
      aq[0] = pack_trunc(bf_lo(xq.x) * c, bf_hi(xq.x) * c);
      aq[1] = pack_trunc(bf_lo(xq.y) * c, bf_hi(xq.y) * c);
      aq[2] = pack_trunc(bf_lo(xq.z) * c, bf_hi(xq.z) * c);
      aq[3] = pack_trunc(bf_lo(xq.w) * c, bf_hi(xq.w) * c);
      u4s8 bw; bw.u = wf;
      acc = __builtin_amdgcn_mfma_f32_16x16x32_bf16(af, bw.s, acc, 0, 0, 0);
    }
    // s_part[btile][j][b=quad*4+r][ch72][d=col]  (R14 layout, squash-compat)
    float* sp = s_part + ((((size_t)blockIdx.x * 10 + j) * 16 + quad * 4) * 72
                          + blockIdx.y) * 16 + col;
    #pragma unroll
    for (int r = 0; r < 4; ++r) sp[(size_t)r * 72 * 16] = acc[r];
  }
}

// squash (R9/R14-proven, unchanged): one wave per (b,j); 18 coalesced loads;
// vsbf holds ACCUMULATED v-sum (R7 lesson).
__global__ __launch_bounds__(256) void caps_squash(
    const float* __restrict__ s_part, float* __restrict__ vsum,
    unsigned int* __restrict__ vsbf_u, float* __restrict__ out, const int round)
{
  const int tid  = threadIdx.x;
  const int w    = tid >> 6;
  const int lane = tid & 63;
  const int bj   = blockIdx.x * 4 + w;
  const int b    = bj / 10, j = bj - b * 10;
  const int btile = b >> 4, brem = b & 15;
  const float* base = s_part + (((size_t)btile * 10 + j) * 16 + brem) * 1152;
  float acc = 0.f;
  #pragma unroll
  for (int q = 0; q < 18; ++q) acc += base[q * 64 + lane];
  acc += __shfl_xor(acc, 16, 64);
  acc += __shfl_xor(acc, 32, 64);
  const float s = acc;
  float sq = s * s;
  sq += __shfl_xor(sq, 1, 16);
  sq += __shfl_xor(sq, 2, 16);
  sq += __shfl_xor(sq, 4, 16);
  sq += __shfl_xor(sq, 8, 16);
  const float coef = (sq / (1.f + sq)) * rsqrtf(sq + 1e-7f);
  const float v = coef * s;
  if (round < 2) {
    const float vprev = (lane < 16) ? vsum[bj * 16 + lane] : 0.f;
    const float vt = vprev + v;
    const float vtn = __shfl_down(vt, 1, 64);
    if (lane < 16) {
      vsum[bj * 16 + lane] = vt;
      if (!(lane & 1))
        vsbf_u[bj * 8 + (lane >> 1)] = pack_rne(vt, vtn);
    }
  } else if (lane < 16) {
    out[bj * 16 + lane] = v;
  }
}

extern "C" void kernel_launch(void* const* d_in, const int* in_sizes, int n_in,
                              void* d_out, int out_size, void* d_ws, size_t ws_size,
                              hipStream_t stream)
{
  const float* x_p = (const float*)d_in[0];   // [256][1152][8] fp32
  const float* W_p = (const float*)d_in[1];   // [10][1152][16][8] fp32

  // ws: wsf 2.95M | wcc2 2.95M | s_part 11.8M | vsum 164K | vsbf 82K (~18 MB)
  uint4* wsf   = (uint4*)d_ws;
  uint4* wcc2  = wsf + 184320;
  float* s_prt = (float*)(wcc2 + 184320);             // 2949120 f
  float* vsum  = s_prt + 2949120;                     // 40960 f
  unsigned int* vsbf_u = (unsigned int*)(vsum + 40960);
  float* out_p = (float*)d_out;

  caps_prep<<<dim3(720), dim3(256), 0, stream>>>(W_p, wsf, wcc2, vsum);
  for (int r = 0; r < 3; ++r) {
    caps_pass<<<dim3(16, 72), dim3(320), 0, stream>>>(
        x_p, wsf, wcc2, (const uint4*)vsbf_u, s_prt, r);
    caps_squash<<<dim3(640), dim3(256), 0, stream>>>(
        s_prt, vsum, vsbf_u, out_p, r);
  }
}